// Round 4
// baseline (553.527 us; speedup 1.0000x reference)
//
#include <hip/hip_runtime.h>
#include <math.h>

#define NN 100000
#define NE 1600000
#define NCH 98   // ceil(NN/1024)

__device__ __forceinline__ float lrelu(float t) { return t >= 0.0f ? t : 0.2f * t; }

// h = x @ W^T (fp64 acc), att logits a_src/a_dst via per-head shuffle reduce.
__global__ __launch_bounds__(256) void k_proj(
    const float* __restrict__ x, const float* __restrict__ pw,
    const float* __restrict__ atts, const float* __restrict__ attd,
    float* __restrict__ h, float* __restrict__ asrc, float* __restrict__ adst) {
    __shared__ float w[64][65];
    __shared__ float xs[4][64];
    int tid = threadIdx.x;
    for (int i = tid; i < 4096; i += 256) w[i >> 6][i & 63] = pw[i];
    int lane = tid & 63, wv = tid >> 6;
    float aw = atts[lane], dw = attd[lane];
    __syncthreads();
    for (int base = blockIdx.x * 4; base < NN; base += gridDim.x * 4) {
        int row = base + wv;
        bool ok = row < NN;
        xs[wv][lane] = ok ? x[row * 64 + lane] : 0.0f;  // same-wave LDS: no barrier
        double acc = 0.0;
        #pragma unroll
        for (int k = 0; k < 64; ++k)
            acc += (double)xs[wv][k] * (double)w[lane][k];
        double s = acc * (double)aw, d = acc * (double)dw;
        #pragma unroll
        for (int off = 8; off; off >>= 1) {
            s += __shfl_xor(s, off);
            d += __shfl_xor(d, off);
        }
        if (ok) {
            h[row * 64 + lane] = (float)acc;
            if ((lane & 15) == 0) {
                asrc[row * 4 + (lane >> 4)] = (float)s;
                adst[row * 4 + (lane >> 4)] = (float)d;
            }
        }
    }
}

__global__ __launch_bounds__(256) void k_count(const int* __restrict__ ei, int* __restrict__ cnt) {
    int e = blockIdx.x * 256 + threadIdx.x;
    if (e < NE) atomicAdd(&cnt[ei[NE + e]], 1);
}

// in-place exclusive scan of cnt per 1024-chunk; chunk totals to part[]
__global__ __launch_bounds__(1024) void k_scan1(int* __restrict__ cnt, int* __restrict__ part) {
    __shared__ int s[1024];
    int tid = threadIdx.x, i = blockIdx.x * 1024 + tid;
    int v = (i < NN) ? cnt[i] : 0;
    s[tid] = v; __syncthreads();
    for (int off = 1; off < 1024; off <<= 1) {
        int t = (tid >= off) ? s[tid - off] : 0; __syncthreads();
        s[tid] += t; __syncthreads();
    }
    if (i < NN) cnt[i] = s[tid] - v;                 // exclusive within chunk
    if (tid == 1023) part[blockIdx.x] = s[1023];     // chunk total
}

// parallel exclusive scan of the 98 chunk totals (one block)
__global__ __launch_bounds__(128) void k_scan2(int* __restrict__ part) {
    __shared__ int s[128];
    int tid = threadIdx.x;
    int v = (tid < NCH) ? part[tid] : 0;
    s[tid] = v; __syncthreads();
    for (int off = 1; off < 128; off <<= 1) {
        int t = (tid >= off) ? s[tid - off] : 0; __syncthreads();
        s[tid] += t; __syncthreads();
    }
    if (tid < NCH) part[tid] = s[tid] - v;           // exclusive
}

__global__ __launch_bounds__(1024) void k_scan3(
    const int* __restrict__ cnt, const int* __restrict__ part,
    int* __restrict__ rowptr, int* __restrict__ fill) {
    int i = blockIdx.x * 1024 + threadIdx.x;
    if (i < NN) { int rp = cnt[i] + part[i >> 10]; rowptr[i] = rp; fill[i] = rp; }
    if (i == 0) rowptr[NN] = NE;
}

__global__ __launch_bounds__(256) void k_scatter(
    const int* __restrict__ ei, int* __restrict__ fill, int* __restrict__ csr) {
    int e = blockIdx.x * 256 + threadIdx.x;
    if (e < NE) {
        int s = ei[e], d = ei[NE + e];
        int pos = atomicAdd(&fill[d], 1);
        csr[pos] = s;
    }
}

// fused per-node: softmax over incident edges + gather-agg + mean + GEMM + norm + threshold
__global__ __launch_bounds__(256) void k_node(
    const int* __restrict__ rowptr, const int* __restrict__ csr,
    const float* __restrict__ asrc, const float* __restrict__ adst,
    const float* __restrict__ h, const float* __restrict__ po,
    const float* __restrict__ gamma, const float* __restrict__ beta,
    float* __restrict__ out) {
    __shared__ float w[64][65];
    __shared__ double am[4][64];
    __shared__ __align__(16) float exl[4][64][4];
    __shared__ int sl[4][64];
    int tid = threadIdx.x;
    for (int i = tid; i < 4096; i += 256) w[i >> 6][i & 63] = po[i];
    int lane = tid & 63, wv = tid >> 6, hh = lane >> 4;
    float g = gamma[lane], b = beta[lane];
    __syncthreads();
    const float NINF = __int_as_float(0xff800000);
    for (int n = blockIdx.x * 4 + wv; n < NN; n += gridDim.x * 4) {
        int r0 = rowptr[n], deg = rowptr[n + 1] - r0;
        float4 bd = *(const float4*)(adst + (size_t)n * 4);
        double acc = 0.0;
        if (deg <= 64) {
            int s_e = 0;
            float4 lg = make_float4(NINF, NINF, NINF, NINF);
            if (lane < deg) {
                s_e = csr[r0 + lane];
                float4 av = *(const float4*)(asrc + (size_t)s_e * 4);
                lg.x = lrelu(av.x + bd.x); lg.y = lrelu(av.y + bd.y);
                lg.z = lrelu(av.z + bd.z); lg.w = lrelu(av.w + bd.w);
            }
            float4 mx = lg;
            #pragma unroll
            for (int off = 32; off; off >>= 1) {
                mx.x = fmaxf(mx.x, __shfl_xor(mx.x, off));
                mx.y = fmaxf(mx.y, __shfl_xor(mx.y, off));
                mx.z = fmaxf(mx.z, __shfl_xor(mx.z, off));
                mx.w = fmaxf(mx.w, __shfl_xor(mx.w, off));
            }
            float4 ex = make_float4(0.f, 0.f, 0.f, 0.f);
            if (lane < deg) {
                ex.x = expf(lg.x - mx.x); ex.y = expf(lg.y - mx.y);
                ex.z = expf(lg.z - mx.z); ex.w = expf(lg.w - mx.w);
            }
            double s0 = ex.x, s1 = ex.y, s2 = ex.z, s3 = ex.w;
            #pragma unroll
            for (int off = 32; off; off >>= 1) {
                s0 += __shfl_xor(s0, off); s1 += __shfl_xor(s1, off);
                s2 += __shfl_xor(s2, off); s3 += __shfl_xor(s3, off);
            }
            sl[wv][lane] = s_e;                       // same-wave LDS, no barrier
            *(float4*)&exl[wv][lane][0] = ex;
            double den = hh == 0 ? s0 : hh == 1 ? s1 : hh == 2 ? s2 : s3;
            double inv = 1.0 / (den + 1e-16);
            // software-pipelined gather: batch k+1 loads issue before batch k FMAs
            double acA = 0.0, acB = 0.0, acC = 0.0, acD = 0.0;
            int e = 0;
            if (deg >= 4) {
                float f0 = h[(size_t)sl[wv][0] * 64 + lane];
                float f1 = h[(size_t)sl[wv][1] * 64 + lane];
                float f2 = h[(size_t)sl[wv][2] * 64 + lane];
                float f3 = h[(size_t)sl[wv][3] * 64 + lane];
                for (e = 4; e + 4 <= deg; e += 4) {
                    float g0 = h[(size_t)sl[wv][e + 0] * 64 + lane];
                    float g1 = h[(size_t)sl[wv][e + 1] * 64 + lane];
                    float g2 = h[(size_t)sl[wv][e + 2] * 64 + lane];
                    float g3 = h[(size_t)sl[wv][e + 3] * 64 + lane];
                    acA += (double)exl[wv][e - 4][hh] * inv * (double)f0;
                    acB += (double)exl[wv][e - 3][hh] * inv * (double)f1;
                    acC += (double)exl[wv][e - 2][hh] * inv * (double)f2;
                    acD += (double)exl[wv][e - 1][hh] * inv * (double)f3;
                    f0 = g0; f1 = g1; f2 = g2; f3 = g3;
                }
                acA += (double)exl[wv][e - 4][hh] * inv * (double)f0;
                acB += (double)exl[wv][e - 3][hh] * inv * (double)f1;
                acC += (double)exl[wv][e - 2][hh] * inv * (double)f2;
                acD += (double)exl[wv][e - 1][hh] * inv * (double)f3;
            }
            for (; e < deg; ++e)
                acA += (double)exl[wv][e][hh] * inv * (double)h[(size_t)sl[wv][e] * 64 + lane];
            acc = (acA + acB) + (acC + acD);
        } else {  // deg > 64: lane-strided, recompute path (statistically never taken)
            float4 mx = make_float4(NINF, NINF, NINF, NINF);
            for (int e = lane; e < deg; e += 64) {
                int s = csr[r0 + e];
                float4 av = *(const float4*)(asrc + (size_t)s * 4);
                mx.x = fmaxf(mx.x, lrelu(av.x + bd.x)); mx.y = fmaxf(mx.y, lrelu(av.y + bd.y));
                mx.z = fmaxf(mx.z, lrelu(av.z + bd.z)); mx.w = fmaxf(mx.w, lrelu(av.w + bd.w));
            }
            #pragma unroll
            for (int off = 32; off; off >>= 1) {
                mx.x = fmaxf(mx.x, __shfl_xor(mx.x, off));
                mx.y = fmaxf(mx.y, __shfl_xor(mx.y, off));
                mx.z = fmaxf(mx.z, __shfl_xor(mx.z, off));
                mx.w = fmaxf(mx.w, __shfl_xor(mx.w, off));
            }
            double s0 = 0, s1 = 0, s2 = 0, s3 = 0;
            for (int e = lane; e < deg; e += 64) {
                int s = csr[r0 + e];
                float4 av = *(const float4*)(asrc + (size_t)s * 4);
                s0 += (double)expf(lrelu(av.x + bd.x) - mx.x);
                s1 += (double)expf(lrelu(av.y + bd.y) - mx.y);
                s2 += (double)expf(lrelu(av.z + bd.z) - mx.z);
                s3 += (double)expf(lrelu(av.w + bd.w) - mx.w);
            }
            #pragma unroll
            for (int off = 32; off; off >>= 1) {
                s0 += __shfl_xor(s0, off); s1 += __shfl_xor(s1, off);
                s2 += __shfl_xor(s2, off); s3 += __shfl_xor(s3, off);
            }
            double den = hh == 0 ? s0 : hh == 1 ? s1 : hh == 2 ? s2 : s3;
            double inv = 1.0 / (den + 1e-16);
            float mxh = hh == 0 ? mx.x : hh == 1 ? mx.y : hh == 2 ? mx.z : mx.w;
            float bdh = hh == 0 ? bd.x : hh == 1 ? bd.y : hh == 2 ? bd.z : bd.w;
            for (int e = 0; e < deg; ++e) {
                int s = csr[r0 + e];
                float ev = lrelu(asrc[(size_t)s * 4 + hh] + bdh);
                float exe = expf(ev - mxh);
                acc += (double)exe * inv * (double)h[(size_t)s * 64 + lane];
            }
        }
        double invc = 1.0 / (double)(deg > 0 ? deg : 1);
        am[wv][lane] = acc * invc;                    // same-wave LDS
        double a2 = 0.0;
        #pragma unroll
        for (int k = 0; k < 64; ++k) a2 += (double)w[lane][k] * am[wv][k];
        double sum = a2;
        #pragma unroll
        for (int off = 32; off; off >>= 1) sum += __shfl_xor(sum, off);
        double mean = sum * (1.0 / 64.0);
        double dv = a2 - mean, sq = dv * dv;
        #pragma unroll
        for (int off = 32; off; off >>= 1) sq += __shfl_xor(sq, off);
        double var = sq * (1.0 / 64.0);
        double z = dv / sqrt(var + 1e-5);
        float zf = (float)(z * (double)g + (double)b);
        out[(size_t)n * 64 + lane] = (zf >= 2.0f) ? 1.0f : 0.0f;  // LIF fwd == z >= 2
    }
}

extern "C" void kernel_launch(void* const* d_in, const int* in_sizes, int n_in,
                              void* d_out, int out_size, void* d_ws, size_t ws_size,
                              hipStream_t stream) {
    const float* x     = (const float*)d_in[0];
    const int*   ei    = (const int*)d_in[1];   // harness pushes integers as int32
    const float* pw    = (const float*)d_in[2];
    const float* po    = (const float*)d_in[3];
    const float* atts  = (const float*)d_in[4];
    const float* attd  = (const float*)d_in[5];
    const float* gamma = (const float*)d_in[6];
    const float* beta  = (const float*)d_in[7];
    float* out = (float*)d_out;

    char* base = (char*)d_ws;
    size_t off = 0;
    auto alloc = [&](size_t b) { void* p = base + off; off += (b + 255) & ~(size_t)255; return p; };
    float* h      = (float*)alloc((size_t)NN * 64 * 4);
    float* asrc   = (float*)alloc((size_t)NN * 16);
    float* adst   = (float*)alloc((size_t)NN * 16);
    int*   rowptr = (int*)alloc(((size_t)NN + 1) * 4);
    int*   csr    = (int*)alloc((size_t)NE * 4);
    int*   part   = (int*)alloc((size_t)NCH * 4);
    // cnt & fill alias d_out (only live before k_node, which overwrites all of out)
    int* fill = (int*)out;
    int* cnt  = (int*)out + NN;

    hipMemsetAsync(cnt, 0, (size_t)NN * 4, stream);
    k_count<<<NE / 256, 256, 0, stream>>>(ei, cnt);
    k_scan1<<<NCH, 1024, 0, stream>>>(cnt, part);
    k_scan2<<<1, 128, 0, stream>>>(part);
    k_scan3<<<NCH, 1024, 0, stream>>>(cnt, part, rowptr, fill);
    k_scatter<<<NE / 256, 256, 0, stream>>>(ei, fill, csr);
    k_proj<<<1024, 256, 0, stream>>>(x, pw, atts, attd, h, asrc, adst);
    k_node<<<6250, 256, 0, stream>>>(rowptr, csr, asrc, adst, h, po, gamma, beta, out);
}

// Round 5
// 484.862 us; speedup vs baseline: 1.1416x; 1.1416x over previous
//
#include <hip/hip_runtime.h>
#include <math.h>

#define NN 100000
#define NE 1600000
#define NCH 98   // ceil(NN/1024)

__device__ __forceinline__ float lrelu(float t) { return t >= 0.0f ? t : 0.2f * t; }

// h = x @ W^T (fp64 acc), att logits a_src/a_dst via per-head shuffle reduce.
__global__ __launch_bounds__(256) void k_proj(
    const float* __restrict__ x, const float* __restrict__ pw,
    const float* __restrict__ atts, const float* __restrict__ attd,
    float* __restrict__ h, float* __restrict__ asrc, float* __restrict__ adst) {
    __shared__ float w[64][65];
    __shared__ float xs[4][64];
    int tid = threadIdx.x;
    for (int i = tid; i < 4096; i += 256) w[i >> 6][i & 63] = pw[i];
    int lane = tid & 63, wv = tid >> 6;
    float aw = atts[lane], dw = attd[lane];
    __syncthreads();
    for (int base = blockIdx.x * 4; base < NN; base += gridDim.x * 4) {
        int row = base + wv;
        bool ok = row < NN;
        xs[wv][lane] = ok ? x[row * 64 + lane] : 0.0f;  // same-wave LDS: no barrier
        double acc = 0.0;
        #pragma unroll
        for (int k = 0; k < 64; ++k)
            acc += (double)xs[wv][k] * (double)w[lane][k];
        double s = acc * (double)aw, d = acc * (double)dw;
        #pragma unroll
        for (int off = 8; off; off >>= 1) {
            s += __shfl_xor(s, off);
            d += __shfl_xor(d, off);
        }
        if (ok) {
            h[row * 64 + lane] = (float)acc;
            if ((lane & 15) == 0) {
                asrc[row * 4 + (lane >> 4)] = (float)s;
                adst[row * 4 + (lane >> 4)] = (float)d;
            }
        }
    }
}

// count in-degree; record each edge's arrival rank (removes atomics from scatter)
__global__ __launch_bounds__(256) void k_count(
    const int* __restrict__ ei, int* __restrict__ cnt, int* __restrict__ rank) {
    int e = blockIdx.x * 256 + threadIdx.x;
    if (e < NE) rank[e] = atomicAdd(&cnt[ei[NE + e]], 1);
}

// in-place exclusive scan of cnt per 1024-chunk; chunk totals to part[]
__global__ __launch_bounds__(1024) void k_scan1(int* __restrict__ cnt, int* __restrict__ part) {
    __shared__ int s[1024];
    int tid = threadIdx.x, i = blockIdx.x * 1024 + tid;
    int v = (i < NN) ? cnt[i] : 0;
    s[tid] = v; __syncthreads();
    for (int off = 1; off < 1024; off <<= 1) {
        int t = (tid >= off) ? s[tid - off] : 0; __syncthreads();
        s[tid] += t; __syncthreads();
    }
    if (i < NN) cnt[i] = s[tid] - v;                 // exclusive within chunk
    if (tid == 1023) part[blockIdx.x] = s[1023];     // chunk total
}

// parallel exclusive scan of the 98 chunk totals (one block)
__global__ __launch_bounds__(128) void k_scan2(int* __restrict__ part) {
    __shared__ int s[128];
    int tid = threadIdx.x;
    int v = (tid < NCH) ? part[tid] : 0;
    s[tid] = v; __syncthreads();
    for (int off = 1; off < 128; off <<= 1) {
        int t = (tid >= off) ? s[tid - off] : 0; __syncthreads();
        s[tid] += t; __syncthreads();
    }
    if (tid < NCH) part[tid] = s[tid] - v;           // exclusive
}

__global__ __launch_bounds__(1024) void k_scan3(
    const int* __restrict__ cnt, const int* __restrict__ part, int* __restrict__ rowptr) {
    int i = blockIdx.x * 1024 + threadIdx.x;
    if (i < NN) rowptr[i] = cnt[i] + part[i >> 10];
    if (i == 0) rowptr[NN] = NE;
}

// atomic-free scatter: slot = rowptr[d] + rank[e]
__global__ __launch_bounds__(256) void k_scatter(
    const int* __restrict__ ei, const int* __restrict__ rowptr,
    const int* __restrict__ rank, int* __restrict__ csr) {
    int e = blockIdx.x * 256 + threadIdx.x;
    if (e < NE) {
        int d = ei[NE + e];
        csr[rowptr[d] + rank[e]] = ei[e];
    }
}

// fused per-node: softmax + gather-agg + mean + GEMM + norm + threshold.
// Each wave owns exactly 4 nodes (100000 = 6250*4*4). All long-latency loads
// (csr indices, asrc logits for all 4 nodes; 24-deep h rows per node) are
// issued ahead of the compute that hides them; node k+1's h-gather is issued
// before node k's GEMM.
__global__ __launch_bounds__(256) void k_node(
    const int* __restrict__ rowptr, const int* __restrict__ csr,
    const float* __restrict__ asrc, const float* __restrict__ adst,
    const float* __restrict__ h, const float* __restrict__ po,
    const float* __restrict__ gamma, const float* __restrict__ beta,
    float* __restrict__ out) {
    __shared__ float w[64][65];
    __shared__ double am[4][64];
    __shared__ __align__(16) float exl[4][64][4];
    int tid = threadIdx.x;
    for (int i = tid; i < 4096; i += 256) w[i >> 6][i & 63] = po[i];
    int lane = tid & 63, wv = tid >> 6, hh = lane >> 4;
    float g = gamma[lane], b = beta[lane];
    __syncthreads();
    const float NINF = __int_as_float(0xff800000);
    const int base = blockIdx.x * 4 + wv;            // 0..24999, wave-uniform

    int r0[4], dg[4], se[4];
    float4 av[4], bd[4];
    #pragma unroll
    for (int k = 0; k < 4; ++k) {
        int n = base + k * 25000;
        r0[k] = rowptr[n];
        dg[k] = rowptr[n + 1] - r0[k];
        bd[k] = *(const float4*)(adst + (size_t)n * 4);
    }
    #pragma unroll
    for (int k = 0; k < 4; ++k) {
        se[k] = 0;
        if (lane < dg[k]) se[k] = csr[r0[k] + lane];
    }
    #pragma unroll
    for (int k = 0; k < 4; ++k) {
        av[k] = make_float4(0.f, 0.f, 0.f, 0.f);
        if (lane < dg[k]) av[k] = *(const float4*)(asrc + (size_t)se[k] * 4);
    }

    float f[24];
    #pragma unroll
    for (int t = 0; t < 24; ++t) {                   // h prefetch, node 0
        int st = __builtin_amdgcn_readlane(se[0], t);
        f[t] = (t < dg[0]) ? h[(size_t)st * 64 + lane] : 0.0f;
    }

    #pragma unroll
    for (int k = 0; k < 4; ++k) {
        const int n = base + k * 25000;
        const int deg = dg[k];
        double acc;
        if (deg <= 64) {
            float4 lg = make_float4(NINF, NINF, NINF, NINF);
            if (lane < deg) {
                lg.x = lrelu(av[k].x + bd[k].x); lg.y = lrelu(av[k].y + bd[k].y);
                lg.z = lrelu(av[k].z + bd[k].z); lg.w = lrelu(av[k].w + bd[k].w);
            }
            float4 mx = lg;
            #pragma unroll
            for (int off = 32; off; off >>= 1) {
                mx.x = fmaxf(mx.x, __shfl_xor(mx.x, off));
                mx.y = fmaxf(mx.y, __shfl_xor(mx.y, off));
                mx.z = fmaxf(mx.z, __shfl_xor(mx.z, off));
                mx.w = fmaxf(mx.w, __shfl_xor(mx.w, off));
            }
            float4 ex = make_float4(0.f, 0.f, 0.f, 0.f);
            if (lane < deg) {
                ex.x = expf(lg.x - mx.x); ex.y = expf(lg.y - mx.y);
                ex.z = expf(lg.z - mx.z); ex.w = expf(lg.w - mx.w);
            }
            *(float4*)&exl[wv][lane][0] = ex;        // same-wave LDS
            double s0 = ex.x, s1 = ex.y, s2 = ex.z, s3 = ex.w;
            #pragma unroll
            for (int off = 32; off; off >>= 1) {
                s0 += __shfl_xor(s0, off); s1 += __shfl_xor(s1, off);
                s2 += __shfl_xor(s2, off); s3 += __shfl_xor(s3, off);
            }
            double den = hh == 0 ? s0 : hh == 1 ? s1 : hh == 2 ? s2 : s3;
            double inv = 1.0 / (den + 1e-16);
            double a0 = 0, a1 = 0, a2 = 0, a3 = 0;
            #pragma unroll
            for (int t = 0; t < 24; t += 4) {        // exl[t]=0 & f[t]=0 for t>=deg
                a0 += (double)exl[wv][t + 0][hh] * (double)f[t + 0];
                a1 += (double)exl[wv][t + 1][hh] * (double)f[t + 1];
                a2 += (double)exl[wv][t + 2][hh] * (double)f[t + 2];
                a3 += (double)exl[wv][t + 3][hh] * (double)f[t + 3];
            }
            for (int e2 = 24; e2 < deg; ++e2) {      // rare tail (P~2%)
                int st = __builtin_amdgcn_readlane(se[k], e2);
                a0 += (double)exl[wv][e2][hh] * (double)h[(size_t)st * 64 + lane];
            }
            acc = ((a0 + a1) + (a2 + a3)) * inv;
        } else {                                     // deg>64: unreachable-in-practice serial path
            float bdh = hh == 0 ? bd[k].x : hh == 1 ? bd[k].y : hh == 2 ? bd[k].z : bd[k].w;
            float mxh = NINF;
            for (int e2 = 0; e2 < deg; ++e2) {
                int s = csr[r0[k] + e2];
                mxh = fmaxf(mxh, lrelu(asrc[(size_t)s * 4 + hh] + bdh));
            }
            double den = 0.0, aA = 0.0;
            for (int e2 = 0; e2 < deg; ++e2) {
                int s = csr[r0[k] + e2];
                den += (double)expf(lrelu(asrc[(size_t)s * 4 + hh] + bdh) - mxh);
            }
            for (int e2 = 0; e2 < deg; ++e2) {
                int s = csr[r0[k] + e2];
                float exe = expf(lrelu(asrc[(size_t)s * 4 + hh] + bdh) - mxh);
                aA += (double)exe * (double)h[(size_t)s * 64 + lane];
            }
            acc = aA / (den + 1e-16);
        }
        double invc = 1.0 / (double)(deg > 0 ? deg : 1);
        am[wv][lane] = acc * invc;                   // same-wave LDS

        if (k < 3) {                                 // issue next node's h loads BEFORE the GEMM
            #pragma unroll
            for (int t = 0; t < 24; ++t) {
                int st = __builtin_amdgcn_readlane(se[k + 1], t);
                f[t] = (t < dg[k + 1]) ? h[(size_t)st * 64 + lane] : 0.0f;
            }
        }

        double a2s = 0.0;
        #pragma unroll
        for (int kk = 0; kk < 64; ++kk) a2s += (double)w[lane][kk] * am[wv][kk];
        double sum = a2s;
        #pragma unroll
        for (int off = 32; off; off >>= 1) sum += __shfl_xor(sum, off);
        double mean = sum * (1.0 / 64.0);
        double dv = a2s - mean, sq = dv * dv;
        #pragma unroll
        for (int off = 32; off; off >>= 1) sq += __shfl_xor(sq, off);
        double var = sq * (1.0 / 64.0);
        double z = dv / sqrt(var + 1e-5);
        float zf = (float)(z * (double)g + (double)b);
        out[(size_t)n * 64 + lane] = (zf >= 2.0f) ? 1.0f : 0.0f;  // LIF fwd == z >= 2
    }
}

extern "C" void kernel_launch(void* const* d_in, const int* in_sizes, int n_in,
                              void* d_out, int out_size, void* d_ws, size_t ws_size,
                              hipStream_t stream) {
    const float* x     = (const float*)d_in[0];
    const int*   ei    = (const int*)d_in[1];   // harness pushes integers as int32
    const float* pw    = (const float*)d_in[2];
    const float* po    = (const float*)d_in[3];
    const float* atts  = (const float*)d_in[4];
    const float* attd  = (const float*)d_in[5];
    const float* gamma = (const float*)d_in[6];
    const float* beta  = (const float*)d_in[7];
    float* out = (float*)d_out;

    char* base = (char*)d_ws;
    size_t off = 0;
    auto alloc = [&](size_t b) { void* p = base + off; off += (b + 255) & ~(size_t)255; return p; };
    float* h      = (float*)alloc((size_t)NN * 64 * 4);
    float* asrc   = (float*)alloc((size_t)NN * 16);
    float* adst   = (float*)alloc((size_t)NN * 16);
    int*   rowptr = (int*)alloc(((size_t)NN + 1) * 4);
    int*   csr    = (int*)alloc((size_t)NE * 4);
    int*   rank   = (int*)alloc((size_t)NE * 4);
    int*   part   = (int*)alloc((size_t)NCH * 4);
    // cnt aliases d_out (only live before k_node, which overwrites all of out)
    int* cnt = (int*)out;

    hipMemsetAsync(cnt, 0, (size_t)NN * 4, stream);
    k_count<<<NE / 256, 256, 0, stream>>>(ei, cnt, rank);
    k_scan1<<<NCH, 1024, 0, stream>>>(cnt, part);
    k_scan2<<<1, 128, 0, stream>>>(part);
    k_scan3<<<NCH, 1024, 0, stream>>>(cnt, part, rowptr);
    k_scatter<<<NE / 256, 256, 0, stream>>>(ei, rowptr, rank, csr);
    k_proj<<<1024, 256, 0, stream>>>(x, pw, atts, attd, h, asrc, adst);
    k_node<<<6250, 256, 0, stream>>>(rowptr, csr, asrc, adst, h, po, gamma, beta, out);
}

// Round 7
// 405.729 us; speedup vs baseline: 1.3643x; 1.1950x over previous
//
#include <hip/hip_runtime.h>
#include <math.h>

#define NN 100000
#define NE 1600000
#define NCH 98   // ceil(NN/1024)

__device__ __forceinline__ float lrelu(float t) { return t >= 0.0f ? t : 0.2f * t; }

// h = x @ W^T (fp64 acc, W row in registers); logits reduced in fp64.
__global__ __launch_bounds__(256) void k_proj(
    const float* __restrict__ x, const float* __restrict__ pw,
    const float* __restrict__ atts, const float* __restrict__ attd,
    float* __restrict__ h, float* __restrict__ asrc, float* __restrict__ adst) {
    __shared__ __align__(16) float w[64][68];   // 68*4B=272B rows: 16B-aligned, banks balanced
    __shared__ __align__(16) float xs[4][68];
    int tid = threadIdx.x;
    for (int i = tid; i < 4096; i += 256) w[i >> 6][i & 63] = pw[i];
    int lane = tid & 63, wv = tid >> 6;
    double aw = (double)atts[lane], dw = (double)attd[lane];
    __syncthreads();
    float4 wr[16];                               // my output row of W (64 VGPR)
    #pragma unroll
    for (int j = 0; j < 16; ++j) wr[j] = *(const float4*)&w[lane][4 * j];
    for (int base = blockIdx.x * 4; base < NN; base += gridDim.x * 4) {
        int row = base + wv;
        bool ok = row < NN;
        xs[wv][lane] = ok ? x[row * 64 + lane] : 0.0f;   // same-wave LDS
        double acc = 0.0;
        #pragma unroll
        for (int j = 0; j < 16; ++j) {
            float4 xv = *(const float4*)&xs[wv][4 * j];  // broadcast b128
            acc += (double)wr[j].x * (double)xv.x;
            acc += (double)wr[j].y * (double)xv.y;
            acc += (double)wr[j].z * (double)xv.z;
            acc += (double)wr[j].w * (double)xv.w;
        }
        float hf = (float)acc;
        double s = (double)hf * aw, d = (double)hf * dw; // fp64 reduce (rounds 2-5 class)
        #pragma unroll
        for (int off = 8; off; off >>= 1) {              // 16-lane head reduce
            s += __shfl_xor(s, off);
            d += __shfl_xor(d, off);
        }
        if (ok) {
            h[row * 64 + lane] = hf;
            if ((lane & 15) == 0) {
                asrc[row * 4 + (lane >> 4)] = (float)s;
                adst[row * 4 + (lane >> 4)] = (float)d;
            }
        }
    }
}

__global__ __launch_bounds__(256) void k_count(
    const int* __restrict__ ei, int* __restrict__ cnt, int* __restrict__ rank) {
    int e = blockIdx.x * 256 + threadIdx.x;
    if (e < NE) rank[e] = atomicAdd(&cnt[ei[NE + e]], 1);
}

__global__ __launch_bounds__(1024) void k_scan1(int* __restrict__ cnt, int* __restrict__ part) {
    __shared__ int s[1024];
    int tid = threadIdx.x, i = blockIdx.x * 1024 + tid;
    int v = (i < NN) ? cnt[i] : 0;
    s[tid] = v; __syncthreads();
    for (int off = 1; off < 1024; off <<= 1) {
        int t = (tid >= off) ? s[tid - off] : 0; __syncthreads();
        s[tid] += t; __syncthreads();
    }
    if (i < NN) cnt[i] = s[tid] - v;
    if (tid == 1023) part[blockIdx.x] = s[1023];
}

__global__ __launch_bounds__(128) void k_scan2(int* __restrict__ part) {
    __shared__ int s[128];
    int tid = threadIdx.x;
    int v = (tid < NCH) ? part[tid] : 0;
    s[tid] = v; __syncthreads();
    for (int off = 1; off < 128; off <<= 1) {
        int t = (tid >= off) ? s[tid - off] : 0; __syncthreads();
        s[tid] += t; __syncthreads();
    }
    if (tid < NCH) part[tid] = s[tid] - v;
}

__global__ __launch_bounds__(1024) void k_scan3(
    const int* __restrict__ cnt, const int* __restrict__ part, int* __restrict__ rowptr) {
    int i = blockIdx.x * 1024 + threadIdx.x;
    if (i < NN) rowptr[i] = cnt[i] + part[i >> 10];
    if (i == 0) rowptr[NN] = NE;
}

__global__ __launch_bounds__(256) void k_scatter(
    const int* __restrict__ ei, const int* __restrict__ rowptr,
    const int* __restrict__ rank, int* __restrict__ csr) {
    int e = blockIdx.x * 256 + threadIdx.x;
    if (e < NE) {
        int d = ei[NE + e];
        csr[rowptr[d] + rank[e]] = ei[e];
    }
}

// Fused per-node kernel. Wave = 4 nodes. lane = 16*eg + cg: edge-group eg,
// channel-quad cg (channels 4cg..4cg+3, head hh=cg>>2). Edge-group eg owns
// edges {4G + eg : 4G < deg} — exact interleaved cover of 0..deg-1 for any deg.
__global__ __launch_bounds__(256) void k_node(
    const int* __restrict__ rowptr, const int* __restrict__ csr,
    const float* __restrict__ asrc, const float* __restrict__ adst,
    const float* __restrict__ h, const float* __restrict__ po,
    const float* __restrict__ gamma, const float* __restrict__ beta,
    float* __restrict__ out) {
    __shared__ __align__(16) float w[64][68];
    __shared__ __align__(16) float am[4][4][68];
    int tid = threadIdx.x;
    for (int i = tid; i < 4096; i += 256) w[i >> 6][i & 63] = po[i];
    int lane = tid & 63, wv = tid >> 6;
    int cg = lane & 15, hh = cg >> 2, eg = lane >> 4;
    float gl = gamma[lane], bl = beta[lane];
    __syncthreads();
    const float NINF = __int_as_float(0xff800000);
    const int nb = blockIdx.x * 4 + wv;          // 0..24999, wave-uniform

    int r0[4], dg[4], se[4];
    #pragma unroll
    for (int k = 0; k < 4; ++k) {
        int n = nb + k * 25000;
        r0[k] = rowptr[n];
        dg[k] = rowptr[n + 1] - r0[k];
    }
    #pragma unroll
    for (int k = 0; k < 4; ++k)
        se[k] = (lane < dg[k]) ? csr[r0[k] + lane] : 0;

    float4 fb0, fb1, fb2, fb3;
#define HLOAD(S) (*(const float4*)(h + ((size_t)(S) << 6) + (cg << 2)))
#define PREF(KK) do { \
        fb0 = HLOAD(__shfl(se[KK], eg));      \
        fb1 = HLOAD(__shfl(se[KK], eg + 4));  \
        fb2 = HLOAD(__shfl(se[KK], eg + 8));  \
        fb3 = HLOAD(__shfl(se[KK], eg + 12)); \
    } while (0)
    PREF(0);                                     // node 0 edges eg..12+eg in flight

    // logits -> per-head max (exact) -> exp (bit-identical to ref's exp(e-m))
    float4 ex[4];
    #pragma unroll
    for (int k = 0; k < 4; ++k) {
        int n = nb + k * 25000;
        float4 bd = *(const float4*)(adst + (size_t)n * 4);   // wave-uniform
        float4 lg = make_float4(NINF, NINF, NINF, NINF);
        if (lane < dg[k]) {
            float4 av = *(const float4*)(asrc + (size_t)se[k] * 4);
            lg.x = lrelu(av.x + bd.x); lg.y = lrelu(av.y + bd.y);
            lg.z = lrelu(av.z + bd.z); lg.w = lrelu(av.w + bd.w);
        }
        float4 mx = lg;
        #pragma unroll
        for (int off = 32; off; off >>= 1) {
            mx.x = fmaxf(mx.x, __shfl_xor(mx.x, off));
            mx.y = fmaxf(mx.y, __shfl_xor(mx.y, off));
            mx.z = fmaxf(mx.z, __shfl_xor(mx.z, off));
            mx.w = fmaxf(mx.w, __shfl_xor(mx.w, off));
        }
        float4 e4 = make_float4(0.f, 0.f, 0.f, 0.f);
        if (lane < dg[k]) {
            e4.x = expf(lg.x - mx.x); e4.y = expf(lg.y - mx.y);
            e4.z = expf(lg.z - mx.z); e4.w = expf(lg.w - mx.w);
        }
        ex[k] = e4;
    }
    // fp64 denominators + combined scale (1/denom)*(1/deg)
    double sc[4];
    #pragma unroll
    for (int k = 0; k < 4; ++k) {
        double d0 = ex[k].x, d1 = ex[k].y, d2 = ex[k].z, d3 = ex[k].w;
        #pragma unroll
        for (int off = 32; off; off >>= 1) {
            d0 += __shfl_xor(d0, off); d1 += __shfl_xor(d1, off);
            d2 += __shfl_xor(d2, off); d3 += __shfl_xor(d3, off);
        }
        double dh = hh == 0 ? d0 : hh == 1 ? d1 : hh == 2 ? d2 : d3;
        sc[k] = (1.0 / (dh + 1e-16)) * (1.0 / (double)(dg[k] > 0 ? dg[k] : 1));
    }

    #pragma unroll
    for (int k = 0; k < 4; ++k) {
        const int deg = dg[k];
        if (deg <= 64) {
            double ac0 = 0, ac1 = 0, ac2 = 0, ac3 = 0;
#define STEP(G, FB) do { if (4 * (G) < deg) { \
            int src_ = 4 * (G) + eg; \
            float axx = __shfl(ex[k].x, src_); \
            float axy = __shfl(ex[k].y, src_); \
            float axz = __shfl(ex[k].z, src_); \
            float axw = __shfl(ex[k].w, src_); \
            float a_ = hh < 2 ? (hh == 0 ? axx : axy) : (hh == 2 ? axz : axw); \
            float4 fv_ = FB; \
            if (4 * ((G) + 4) < deg) { int sr_ = __shfl(se[k], src_ + 16); FB = HLOAD(sr_); } \
            double aD_ = (double)a_; \
            ac0 += aD_ * (double)fv_.x; ac1 += aD_ * (double)fv_.y; \
            ac2 += aD_ * (double)fv_.z; ac3 += aD_ * (double)fv_.w; \
        } } while (0)
            STEP(0, fb0);  STEP(1, fb1);  STEP(2, fb2);  STEP(3, fb3);
            STEP(4, fb0);  STEP(5, fb1);  STEP(6, fb2);  STEP(7, fb3);
            STEP(8, fb0);  STEP(9, fb1);  STEP(10, fb2); STEP(11, fb3);
            STEP(12, fb0); STEP(13, fb1); STEP(14, fb2); STEP(15, fb3);
#undef STEP
            // fp64 reduce over the 4 edge-groups (lanes cg, 16+cg, 32+cg, 48+cg)
            ac0 += __shfl_xor(ac0, 32); ac1 += __shfl_xor(ac1, 32);
            ac2 += __shfl_xor(ac2, 32); ac3 += __shfl_xor(ac3, 32);
            ac0 += __shfl_xor(ac0, 16); ac1 += __shfl_xor(ac1, 16);
            ac2 += __shfl_xor(ac2, 16); ac3 += __shfl_xor(ac3, 16);
            if (eg == 0) {
                float4 amv = make_float4((float)(ac0 * sc[k]), (float)(ac1 * sc[k]),
                                         (float)(ac2 * sc[k]), (float)(ac3 * sc[k]));
                *(float4*)&am[wv][k][4 * cg] = amv;
            }
        } else {
            // rare fallback (deg>64): lane = channel, serial edges, exact max
            int n = nb + k * 25000;
            int hd = lane >> 4;
            float4 bd = *(const float4*)(adst + (size_t)n * 4);
            float bdh = hd == 0 ? bd.x : hd == 1 ? bd.y : hd == 2 ? bd.z : bd.w;
            float mxh = NINF;
            for (int e2 = 0; e2 < deg; ++e2) {
                int s = csr[r0[k] + e2];
                mxh = fmaxf(mxh, lrelu(asrc[(size_t)s * 4 + hd] + bdh));
            }
            double den = 0.0, aA = 0.0;
            for (int e2 = 0; e2 < deg; ++e2) {
                int s = csr[r0[k] + e2];
                float ee = expf(lrelu(asrc[(size_t)s * 4 + hd] + bdh) - mxh);
                den += (double)ee;
                aA += (double)ee * (double)h[(size_t)s * 64 + lane];
            }
            am[wv][k][lane] = (float)(aA / (den + 1e-16) / (double)deg);
        }
        if (k < 3) PREF(k + 1);                  // next node's h in flight before GEMM phase
    }
#undef PREF
#undef HLOAD

    // batched GEMM over the wave's 4 nodes (fp64 accumulate)
    double a2[4] = {0.0, 0.0, 0.0, 0.0};
    #pragma unroll
    for (int j = 0; j < 16; ++j) {
        float4 wv4 = *(const float4*)&w[lane][4 * j];       // per-lane b128
        #pragma unroll
        for (int k = 0; k < 4; ++k) {
            float4 amv = *(const float4*)&am[wv][k][4 * j]; // broadcast b128
            a2[k] += (double)wv4.x * (double)amv.x;
            a2[k] += (double)wv4.y * (double)amv.y;
            a2[k] += (double)wv4.z * (double)amv.z;
            a2[k] += (double)wv4.w * (double)amv.w;
        }
    }
    // per-node norm (fp64 reductions) + threshold
    #pragma unroll
    for (int k = 0; k < 4; ++k) {
        int n = nb + k * 25000;
        double sum = a2[k];
        #pragma unroll
        for (int off = 32; off; off >>= 1) sum += __shfl_xor(sum, off);
        double mean = sum * (1.0 / 64.0);
        double dv = a2[k] - mean, sq = dv * dv;
        #pragma unroll
        for (int off = 32; off; off >>= 1) sq += __shfl_xor(sq, off);
        double var = sq * (1.0 / 64.0);
        double z = dv / sqrt(var + 1e-5);
        float zf = (float)(z * (double)gl + (double)bl);
        out[(size_t)n * 64 + lane] = (zf >= 2.0f) ? 1.0f : 0.0f;  // LIF fwd == z >= 2
    }
}

extern "C" void kernel_launch(void* const* d_in, const int* in_sizes, int n_in,
                              void* d_out, int out_size, void* d_ws, size_t ws_size,
                              hipStream_t stream) {
    const float* x     = (const float*)d_in[0];
    const int*   ei    = (const int*)d_in[1];   // harness pushes integers as int32
    const float* pw    = (const float*)d_in[2];
    const float* po    = (const float*)d_in[3];
    const float* atts  = (const float*)d_in[4];
    const float* attd  = (const float*)d_in[5];
    const float* gamma = (const float*)d_in[6];
    const float* beta  = (const float*)d_in[7];
    float* out = (float*)d_out;

    char* base = (char*)d_ws;
    size_t off = 0;
    auto alloc = [&](size_t b) { void* p = base + off; off += (b + 255) & ~(size_t)255; return p; };
    float* h      = (float*)alloc((size_t)NN * 64 * 4);
    float* asrc   = (float*)alloc((size_t)NN * 16);
    float* adst   = (float*)alloc((size_t)NN * 16);
    int*   rowptr = (int*)alloc(((size_t)NN + 1) * 4);
    int*   csr    = (int*)alloc((size_t)NE * 4);
    int*   rank   = (int*)alloc((size_t)NE * 4);
    int*   part   = (int*)alloc((size_t)NCH * 4);
    // cnt aliases d_out (only live before k_node, which overwrites all of out)
    int* cnt = (int*)out;

    hipMemsetAsync(cnt, 0, (size_t)NN * 4, stream);
    k_count<<<NE / 256, 256, 0, stream>>>(ei, cnt, rank);
    k_scan1<<<NCH, 1024, 0, stream>>>(cnt, part);
    k_scan2<<<1, 128, 0, stream>>>(part);
    k_scan3<<<NCH, 1024, 0, stream>>>(cnt, part, rowptr);
    k_scatter<<<NE / 256, 256, 0, stream>>>(ei, rowptr, rank, csr);
    k_proj<<<1024, 256, 0, stream>>>(x, pw, atts, attd, h, asrc, adst);
    k_node<<<6250, 256, 0, stream>>>(rowptr, csr, asrc, adst, h, po, gamma, beta, out);
}

// Round 8
// 335.307 us; speedup vs baseline: 1.6508x; 1.2100x over previous
//
#include <hip/hip_runtime.h>
#include <math.h>

#define NN 100000
#define NE 1600000
#define NCH 98   // ceil(NN/1024)

__device__ __forceinline__ float lrelu(float t) { return t >= 0.0f ? t : 0.2f * t; }

// h = x @ W^T (fp64 acc, W row in registers); logits reduced in fp64.
__global__ __launch_bounds__(256) void k_proj(
    const float* __restrict__ x, const float* __restrict__ pw,
    const float* __restrict__ atts, const float* __restrict__ attd,
    float* __restrict__ h, float* __restrict__ asrc, float* __restrict__ adst) {
    __shared__ __align__(16) float w[64][68];
    __shared__ __align__(16) float xs[4][68];
    int tid = threadIdx.x;
    for (int i = tid; i < 4096; i += 256) w[i >> 6][i & 63] = pw[i];
    int lane = tid & 63, wv = tid >> 6;
    double aw = (double)atts[lane], dw = (double)attd[lane];
    __syncthreads();
    float4 wr[16];
    #pragma unroll
    for (int j = 0; j < 16; ++j) wr[j] = *(const float4*)&w[lane][4 * j];
    for (int base = blockIdx.x * 4; base < NN; base += gridDim.x * 4) {
        int row = base + wv;
        bool ok = row < NN;
        xs[wv][lane] = ok ? x[row * 64 + lane] : 0.0f;   // same-wave LDS
        double acc = 0.0;
        #pragma unroll
        for (int j = 0; j < 16; ++j) {
            float4 xv = *(const float4*)&xs[wv][4 * j];  // broadcast b128
            acc += (double)wr[j].x * (double)xv.x;
            acc += (double)wr[j].y * (double)xv.y;
            acc += (double)wr[j].z * (double)xv.z;
            acc += (double)wr[j].w * (double)xv.w;
        }
        float hf = (float)acc;
        double s = (double)hf * aw, d = (double)hf * dw;
        #pragma unroll
        for (int off = 8; off; off >>= 1) {              // 16-lane head reduce
            s += __shfl_xor(s, off);
            d += __shfl_xor(d, off);
        }
        if (ok) {
            h[row * 64 + lane] = hf;
            if ((lane & 15) == 0) {
                asrc[row * 4 + (lane >> 4)] = (float)s;
                adst[row * 4 + (lane >> 4)] = (float)d;
            }
        }
    }
}

__global__ __launch_bounds__(256) void k_count(
    const int* __restrict__ ei, int* __restrict__ cnt, int* __restrict__ rank) {
    int e = blockIdx.x * 256 + threadIdx.x;
    if (e < NE) rank[e] = atomicAdd(&cnt[ei[NE + e]], 1);
}

__global__ __launch_bounds__(1024) void k_scan1(int* __restrict__ cnt, int* __restrict__ part) {
    __shared__ int s[1024];
    int tid = threadIdx.x, i = blockIdx.x * 1024 + tid;
    int v = (i < NN) ? cnt[i] : 0;
    s[tid] = v; __syncthreads();
    for (int off = 1; off < 1024; off <<= 1) {
        int t = (tid >= off) ? s[tid - off] : 0; __syncthreads();
        s[tid] += t; __syncthreads();
    }
    if (i < NN) cnt[i] = s[tid] - v;
    if (tid == 1023) part[blockIdx.x] = s[1023];
}

__global__ __launch_bounds__(128) void k_scan2(int* __restrict__ part) {
    __shared__ int s[128];
    int tid = threadIdx.x;
    int v = (tid < NCH) ? part[tid] : 0;
    s[tid] = v; __syncthreads();
    for (int off = 1; off < 128; off <<= 1) {
        int t = (tid >= off) ? s[tid - off] : 0; __syncthreads();
        s[tid] += t; __syncthreads();
    }
    if (tid < NCH) part[tid] = s[tid] - v;
}

__global__ __launch_bounds__(1024) void k_scan3(
    const int* __restrict__ cnt, const int* __restrict__ part, int* __restrict__ rowptr) {
    int i = blockIdx.x * 1024 + threadIdx.x;
    if (i < NN) rowptr[i] = cnt[i] + part[i >> 10];
    if (i == 0) rowptr[NN] = NE;
}

__global__ __launch_bounds__(256) void k_scatter(
    const int* __restrict__ ei, const int* __restrict__ rowptr,
    const int* __restrict__ rank, int* __restrict__ csr) {
    int e = blockIdx.x * 256 + threadIdx.x;
    if (e < NE) {
        int d = ei[NE + e];
        csr[rowptr[d] + rank[e]] = ei[e];
    }
}

// Gather+softmax+aggregate: ONE wave per node. lane = 16*eg + cg.
// Edge-group eg owns edges {4G + eg : 4G < deg}; cg = channel quad, head hh=cg>>2.
// Writes am[n][64] (fp32, alpha-weighted mean of h[src]) to workspace.
__global__ __launch_bounds__(256) void k_agg(
    const int* __restrict__ rowptr, const int* __restrict__ csr,
    const float* __restrict__ asrc, const float* __restrict__ adst,
    const float* __restrict__ h, float* __restrict__ am) {
    int tid = threadIdx.x;
    int lane = tid & 63, wv = tid >> 6;
    int cg = lane & 15, hh = cg >> 2, eg = lane >> 4;
    const float NINF = __int_as_float(0xff800000);
    const int n = blockIdx.x * 4 + wv;           // grid 25000 * 4 waves = NN exactly

    int r0 = rowptr[n];
    int deg = rowptr[n + 1] - r0;
    float4 bd = *(const float4*)(adst + (size_t)n * 4);  // wave-uniform
    int se = (lane < deg) ? csr[r0 + lane] : 0;

#define HLOAD(S) (*(const float4*)(h + ((size_t)(S) << 6) + (cg << 2)))
    if (deg <= 64) {
        float4 fb0 = HLOAD(__shfl(se, eg));      // edges eg, 4+eg, 8+eg, 12+eg in flight
        float4 fb1 = HLOAD(__shfl(se, eg + 4));
        float4 fb2 = HLOAD(__shfl(se, eg + 8));
        float4 fb3 = HLOAD(__shfl(se, eg + 12));

        // logits -> per-head max (exact) -> exp (bit-identical to ref's exp(e-m))
        float4 lg = make_float4(NINF, NINF, NINF, NINF);
        if (lane < deg) {
            float4 av = *(const float4*)(asrc + (size_t)se * 4);
            lg.x = lrelu(av.x + bd.x); lg.y = lrelu(av.y + bd.y);
            lg.z = lrelu(av.z + bd.z); lg.w = lrelu(av.w + bd.w);
        }
        float4 mx = lg;
        #pragma unroll
        for (int off = 32; off; off >>= 1) {
            mx.x = fmaxf(mx.x, __shfl_xor(mx.x, off));
            mx.y = fmaxf(mx.y, __shfl_xor(mx.y, off));
            mx.z = fmaxf(mx.z, __shfl_xor(mx.z, off));
            mx.w = fmaxf(mx.w, __shfl_xor(mx.w, off));
        }
        float4 ex = make_float4(0.f, 0.f, 0.f, 0.f);
        if (lane < deg) {
            ex.x = expf(lg.x - mx.x); ex.y = expf(lg.y - mx.y);
            ex.z = expf(lg.z - mx.z); ex.w = expf(lg.w - mx.w);
        }
        // fp64 denominator + combined scale (1/denom)*(1/deg)
        double d0 = ex.x, d1 = ex.y, d2 = ex.z, d3 = ex.w;
        #pragma unroll
        for (int off = 32; off; off >>= 1) {
            d0 += __shfl_xor(d0, off); d1 += __shfl_xor(d1, off);
            d2 += __shfl_xor(d2, off); d3 += __shfl_xor(d3, off);
        }
        double dh = hh == 0 ? d0 : hh == 1 ? d1 : hh == 2 ? d2 : d3;
        double sc = (1.0 / (dh + 1e-16)) * (1.0 / (double)(deg > 0 ? deg : 1));

        double ac0 = 0, ac1 = 0, ac2 = 0, ac3 = 0;
#define STEP(G, FB) do { if (4 * (G) < deg) { \
        int src_ = 4 * (G) + eg; \
        float axx = __shfl(ex.x, src_); \
        float axy = __shfl(ex.y, src_); \
        float axz = __shfl(ex.z, src_); \
        float axw = __shfl(ex.w, src_); \
        float a_ = hh < 2 ? (hh == 0 ? axx : axy) : (hh == 2 ? axz : axw); \
        float4 fv_ = FB; \
        if (4 * ((G) + 4) < deg) { int sr_ = __shfl(se, src_ + 16); FB = HLOAD(sr_); } \
        double aD_ = (double)a_; \
        ac0 += aD_ * (double)fv_.x; ac1 += aD_ * (double)fv_.y; \
        ac2 += aD_ * (double)fv_.z; ac3 += aD_ * (double)fv_.w; \
    } } while (0)
        STEP(0, fb0);  STEP(1, fb1);  STEP(2, fb2);  STEP(3, fb3);
        STEP(4, fb0);  STEP(5, fb1);  STEP(6, fb2);  STEP(7, fb3);
        STEP(8, fb0);  STEP(9, fb1);  STEP(10, fb2); STEP(11, fb3);
        STEP(12, fb0); STEP(13, fb1); STEP(14, fb2); STEP(15, fb3);
#undef STEP
        // fp64 reduce over the 4 edge-groups (lanes cg, 16+cg, 32+cg, 48+cg)
        ac0 += __shfl_xor(ac0, 32); ac1 += __shfl_xor(ac1, 32);
        ac2 += __shfl_xor(ac2, 32); ac3 += __shfl_xor(ac3, 32);
        ac0 += __shfl_xor(ac0, 16); ac1 += __shfl_xor(ac1, 16);
        ac2 += __shfl_xor(ac2, 16); ac3 += __shfl_xor(ac3, 16);
        if (eg == 0) {
            float4 amv = make_float4((float)(ac0 * sc), (float)(ac1 * sc),
                                     (float)(ac2 * sc), (float)(ac3 * sc));
            *(float4*)(am + (size_t)n * 64 + 4 * cg) = amv;
        }
    } else {
        // rare fallback (deg>64): lane = channel, serial edges, exact max
        int hd = lane >> 4;
        float bdh = hd == 0 ? bd.x : hd == 1 ? bd.y : hd == 2 ? bd.z : bd.w;
        float mxh = NINF;
        for (int e2 = 0; e2 < deg; ++e2) {
            int s = csr[r0 + e2];
            mxh = fmaxf(mxh, lrelu(asrc[(size_t)s * 4 + hd] + bdh));
        }
        double den = 0.0, aA = 0.0;
        for (int e2 = 0; e2 < deg; ++e2) {
            int s = csr[r0 + e2];
            float ee = expf(lrelu(asrc[(size_t)s * 4 + hd] + bdh) - mxh);
            den += (double)ee;
            aA += (double)ee * (double)h[(size_t)s * 64 + lane];
        }
        am[(size_t)n * 64 + lane] = (float)(aA / (den + 1e-16) / (double)deg);
    }
#undef HLOAD
}

// Streaming GEMM + per-node norm + threshold. Wave = 4 nodes (batched over j).
__global__ __launch_bounds__(256) void k_gemm(
    const float* __restrict__ am, const float* __restrict__ po,
    const float* __restrict__ gamma, const float* __restrict__ beta,
    float* __restrict__ out) {
    __shared__ __align__(16) float w[64][68];
    int tid = threadIdx.x;
    for (int i = tid; i < 4096; i += 256) w[i >> 6][i & 63] = po[i];
    int lane = tid & 63, wv = tid >> 6;
    float gl = gamma[lane], bl = beta[lane];
    __syncthreads();
    const int nb = blockIdx.x * 4 + wv;          // 0..24999, wave-uniform

    double a2[4] = {0.0, 0.0, 0.0, 0.0};
    #pragma unroll
    for (int j = 0; j < 16; ++j) {
        float4 wv4 = *(const float4*)&w[lane][4 * j];        // per-lane b128
        #pragma unroll
        for (int k = 0; k < 4; ++k) {
            float4 amv = *(const float4*)(am + (size_t)(nb + k * 25000) * 64 + 4 * j);
            a2[k] += (double)wv4.x * (double)amv.x;
            a2[k] += (double)wv4.y * (double)amv.y;
            a2[k] += (double)wv4.z * (double)amv.z;
            a2[k] += (double)wv4.w * (double)amv.w;
        }
    }
    #pragma unroll
    for (int k = 0; k < 4; ++k) {
        int n = nb + k * 25000;
        double sum = a2[k];
        #pragma unroll
        for (int off = 32; off; off >>= 1) sum += __shfl_xor(sum, off);
        double mean = sum * (1.0 / 64.0);
        double dv = a2[k] - mean, sq = dv * dv;
        #pragma unroll
        for (int off = 32; off; off >>= 1) sq += __shfl_xor(sq, off);
        double var = sq * (1.0 / 64.0);
        double z = dv / sqrt(var + 1e-5);
        float zf = (float)(z * (double)gl + (double)bl);
        out[(size_t)n * 64 + lane] = (zf >= 2.0f) ? 1.0f : 0.0f;  // LIF fwd == z >= 2
    }
}

extern "C" void kernel_launch(void* const* d_in, const int* in_sizes, int n_in,
                              void* d_out, int out_size, void* d_ws, size_t ws_size,
                              hipStream_t stream) {
    const float* x     = (const float*)d_in[0];
    const int*   ei    = (const int*)d_in[1];   // harness pushes integers as int32
    const float* pw    = (const float*)d_in[2];
    const float* po    = (const float*)d_in[3];
    const float* atts  = (const float*)d_in[4];
    const float* attd  = (const float*)d_in[5];
    const float* gamma = (const float*)d_in[6];
    const float* beta  = (const float*)d_in[7];
    float* out = (float*)d_out;

    char* base = (char*)d_ws;
    size_t off = 0;
    auto alloc = [&](size_t b) { void* p = base + off; off += (b + 255) & ~(size_t)255; return p; };
    float* h      = (float*)alloc((size_t)NN * 64 * 4);
    float* asrc   = (float*)alloc((size_t)NN * 16);
    float* adst   = (float*)alloc((size_t)NN * 16);
    int*   rowptr = (int*)alloc(((size_t)NN + 1) * 4);
    int*   csr    = (int*)alloc((size_t)NE * 4);
    int*   rank   = (int*)alloc((size_t)NE * 4);
    int*   part   = (int*)alloc((size_t)NCH * 4);
    float* amw    = (float*)alloc((size_t)NN * 64 * 4);
    // cnt aliases d_out (only live before k_gemm, which overwrites all of out)
    int* cnt = (int*)out;

    hipMemsetAsync(cnt, 0, (size_t)NN * 4, stream);
    k_count<<<NE / 256, 256, 0, stream>>>(ei, cnt, rank);
    k_scan1<<<NCH, 1024, 0, stream>>>(cnt, part);
    k_scan2<<<1, 128, 0, stream>>>(part);
    k_scan3<<<NCH, 1024, 0, stream>>>(cnt, part, rowptr);
    k_scatter<<<NE / 256, 256, 0, stream>>>(ei, rowptr, rank, csr);
    k_proj<<<1024, 256, 0, stream>>>(x, pw, atts, attd, h, asrc, adst);
    k_agg<<<NN / 4, 256, 0, stream>>>(rowptr, csr, asrc, adst, h, amw);
    k_gemm<<<NN / 16, 256, 0, stream>>>(amw, po, gamma, beta, out);
}

// Round 9
// 275.651 us; speedup vs baseline: 2.0081x; 1.2164x over previous
//
#include <hip/hip_runtime.h>
#include <math.h>

#define NN 100000
#define NE 1600000
#define NCH 98           // ceil(NN/1024)
#define PROJ_BLOCKS 1024
#define SCAT_BLOCKS 6250 // NE/256

__device__ __forceinline__ float lrelu(float t) { return t >= 0.0f ? t : 0.2f * t; }

// count in-degree (2 edges/thread); record each edge's arrival rank
__global__ __launch_bounds__(256) void k_count(
    const int* __restrict__ ei, int* __restrict__ cnt, int* __restrict__ rank) {
    int e = (blockIdx.x * 256 + threadIdx.x) * 2;
    if (e < NE) {
        int2 d = *(const int2*)(ei + NE + e);
        rank[e]     = atomicAdd(&cnt[d.x], 1);
        rank[e + 1] = atomicAdd(&cnt[d.y], 1);
    }
}

// in-place exclusive scan of cnt per 1024-chunk; chunk totals to part[]
__global__ __launch_bounds__(1024) void k_scan1(int* __restrict__ cnt, int* __restrict__ part) {
    __shared__ int s[1024];
    int tid = threadIdx.x, i = blockIdx.x * 1024 + tid;
    int v = (i < NN) ? cnt[i] : 0;
    s[tid] = v; __syncthreads();
    for (int off = 1; off < 1024; off <<= 1) {
        int t = (tid >= off) ? s[tid - off] : 0; __syncthreads();
        s[tid] += t; __syncthreads();
    }
    if (i < NN) cnt[i] = s[tid] - v;                 // exclusive within chunk
    if (tid == 1023) part[blockIdx.x] = s[1023];     // chunk total
}

// rowptr[i] = cnt[i] + exclusive-prefix(part)[chunk]; part scanned redundantly per block
__global__ __launch_bounds__(1024) void k_scan23(
    const int* __restrict__ cnt, const int* __restrict__ part, int* __restrict__ rowptr) {
    __shared__ int sI[128], sO[128];
    int tid = threadIdx.x;
    if (tid < 128) { int v = (tid < NCH) ? part[tid] : 0; sI[tid] = v; sO[tid] = v; }
    __syncthreads();
    for (int off = 1; off < 128; off <<= 1) {
        int t = 0;
        if (tid < 128 && tid >= off) t = sI[tid - off];
        __syncthreads();
        if (tid < 128) sI[tid] += t;
        __syncthreads();
    }
    int i = blockIdx.x * 1024 + tid;
    if (i < NN) { int c = i >> 10; rowptr[i] = cnt[i] + (sI[c] - sO[c]); }
    if (i == 0) rowptr[NN] = NE;
}

// Fused independent kernels: blocks [0,PROJ_BLOCKS) = proj, rest = CSR scatter.
// proj blocks first so the long-running compute starts immediately; scatter
// streams through the remaining CU slots concurrently.
__global__ __launch_bounds__(256) void k_sp(
    const int* __restrict__ ei, const int* __restrict__ rowptr,
    const int* __restrict__ rank, int* __restrict__ csr,
    const float* __restrict__ x, const float* __restrict__ pw,
    const float* __restrict__ atts, const float* __restrict__ attd,
    float* __restrict__ h, float* __restrict__ asrc, float* __restrict__ adst) {
    if (blockIdx.x >= PROJ_BLOCKS) {
        int e = (blockIdx.x - PROJ_BLOCKS) * 256 + threadIdx.x;
        if (e < NE) {
            int d = ei[NE + e];
            csr[rowptr[d] + rank[e]] = ei[e];        // atomic-free scatter
        }
        return;
    }
    // ---- proj: h = x @ W^T (fp64 acc, W row in registers); fp64 logit reduce
    __shared__ __align__(16) float w[64][68];
    __shared__ __align__(16) float xs[4][68];
    int tid = threadIdx.x;
    for (int i = tid; i < 4096; i += 256) w[i >> 6][i & 63] = pw[i];
    int lane = tid & 63, wv = tid >> 6;
    double aw = (double)atts[lane], dw = (double)attd[lane];
    __syncthreads();
    float4 wr[16];
    #pragma unroll
    for (int j = 0; j < 16; ++j) wr[j] = *(const float4*)&w[lane][4 * j];
    for (int base = blockIdx.x * 4; base < NN; base += PROJ_BLOCKS * 4) {
        int row = base + wv;
        bool ok = row < NN;
        xs[wv][lane] = ok ? x[row * 64 + lane] : 0.0f;   // same-wave LDS
        double acc = 0.0;
        #pragma unroll
        for (int j = 0; j < 16; ++j) {
            float4 xv = *(const float4*)&xs[wv][4 * j];  // broadcast b128
            acc += (double)wr[j].x * (double)xv.x;
            acc += (double)wr[j].y * (double)xv.y;
            acc += (double)wr[j].z * (double)xv.z;
            acc += (double)wr[j].w * (double)xv.w;
        }
        float hf = (float)acc;
        double s = (double)hf * aw, d = (double)hf * dw;
        #pragma unroll
        for (int off = 8; off; off >>= 1) {              // 16-lane head reduce
            s += __shfl_xor(s, off);
            d += __shfl_xor(d, off);
        }
        if (ok) {
            h[row * 64 + lane] = hf;
            if ((lane & 15) == 0) {
                asrc[row * 4 + (lane >> 4)] = (float)s;
                adst[row * 4 + (lane >> 4)] = (float)d;
            }
        }
    }
}

// Gather+softmax+aggregate: ONE wave per node. lane = 16*eg + cg.
// Edge-group eg owns edges {4G + eg : 4G < deg}. Denominator accumulated as a
// 5th value inside STEP (linearity) — no separate denom butterfly.
__global__ __launch_bounds__(256) void k_agg(
    const int* __restrict__ rowptr, const int* __restrict__ csr,
    const float* __restrict__ asrc, const float* __restrict__ adst,
    const float* __restrict__ h, float* __restrict__ am) {
    int tid = threadIdx.x;
    int lane = tid & 63, wv = tid >> 6;
    int cg = lane & 15, hh = cg >> 2, eg = lane >> 4;
    const float NINF = __int_as_float(0xff800000);
    const int n = blockIdx.x * 4 + wv;           // grid 25000 * 4 waves = NN exactly

    int r0 = rowptr[n];
    int deg = rowptr[n + 1] - r0;
    float4 bd = *(const float4*)(adst + (size_t)n * 4);  // wave-uniform
    int se = (lane < deg) ? csr[r0 + lane] : 0;

#define HLOAD(S) (*(const float4*)(h + ((size_t)(S) << 6) + (cg << 2)))
    if (deg <= 64) {
        float4 fb0 = HLOAD(__shfl(se, eg));      // edges eg, 4+eg, 8+eg, 12+eg in flight
        float4 fb1 = HLOAD(__shfl(se, eg + 4));
        float4 fb2 = HLOAD(__shfl(se, eg + 8));
        float4 fb3 = HLOAD(__shfl(se, eg + 12));

        float4 lg = make_float4(NINF, NINF, NINF, NINF);
        if (lane < deg) {
            float4 av = *(const float4*)(asrc + (size_t)se * 4);
            lg.x = lrelu(av.x + bd.x); lg.y = lrelu(av.y + bd.y);
            lg.z = lrelu(av.z + bd.z); lg.w = lrelu(av.w + bd.w);
        }
        // exact per-head max; adaptive width (deg wave-uniform, edges in low lanes)
        float4 mx = lg;
#define BF(o) do { \
        mx.x = fmaxf(mx.x, __shfl_xor(mx.x, o)); \
        mx.y = fmaxf(mx.y, __shfl_xor(mx.y, o)); \
        mx.z = fmaxf(mx.z, __shfl_xor(mx.z, o)); \
        mx.w = fmaxf(mx.w, __shfl_xor(mx.w, o)); } while (0)
        if (deg > 32)      { BF(32); BF(16); BF(8); BF(4); BF(2); BF(1); }
        else if (deg > 16) { BF(16); BF(8); BF(4); BF(2); BF(1); }
        else               { BF(8); BF(4); BF(2); BF(1); }
#undef BF
        float4 ex = make_float4(0.f, 0.f, 0.f, 0.f);
        if (lane < deg) {
            ex.x = expf(lg.x - mx.x); ex.y = expf(lg.y - mx.y);
            ex.z = expf(lg.z - mx.z); ex.w = expf(lg.w - mx.w);
        }

        double ac0 = 0, ac1 = 0, ac2 = 0, ac3 = 0, ds = 0;
#define STEP(G, FB) do { if (4 * (G) < deg) { \
        int src_ = 4 * (G) + eg; \
        float axx = __shfl(ex.x, src_); \
        float axy = __shfl(ex.y, src_); \
        float axz = __shfl(ex.z, src_); \
        float axw = __shfl(ex.w, src_); \
        float a_ = hh < 2 ? (hh == 0 ? axx : axy) : (hh == 2 ? axz : axw); \
        float4 fv_ = FB; \
        if (4 * ((G) + 4) < deg) { int sr_ = __shfl(se, src_ + 16); FB = HLOAD(sr_); } \
        double aD_ = (double)a_; \
        ds  += aD_; \
        ac0 += aD_ * (double)fv_.x; ac1 += aD_ * (double)fv_.y; \
        ac2 += aD_ * (double)fv_.z; ac3 += aD_ * (double)fv_.w; \
    } } while (0)
        STEP(0, fb0);  STEP(1, fb1);  STEP(2, fb2);  STEP(3, fb3);
        STEP(4, fb0);  STEP(5, fb1);  STEP(6, fb2);  STEP(7, fb3);
        STEP(8, fb0);  STEP(9, fb1);  STEP(10, fb2); STEP(11, fb3);
        STEP(12, fb0); STEP(13, fb1); STEP(14, fb2); STEP(15, fb3);
#undef STEP
        // fp64 reduce over the 4 edge-groups (lanes cg, 16+cg, 32+cg, 48+cg)
        ac0 += __shfl_xor(ac0, 32); ac1 += __shfl_xor(ac1, 32);
        ac2 += __shfl_xor(ac2, 32); ac3 += __shfl_xor(ac3, 32);
        ds  += __shfl_xor(ds, 32);
        ac0 += __shfl_xor(ac0, 16); ac1 += __shfl_xor(ac1, 16);
        ac2 += __shfl_xor(ac2, 16); ac3 += __shfl_xor(ac3, 16);
        ds  += __shfl_xor(ds, 16);
        if (eg == 0) {
            double sc = (1.0 / (ds + 1e-16)) * (1.0 / (double)(deg > 0 ? deg : 1));
            float4 amv = make_float4((float)(ac0 * sc), (float)(ac1 * sc),
                                     (float)(ac2 * sc), (float)(ac3 * sc));
            *(float4*)(am + (size_t)n * 64 + 4 * cg) = amv;
        }
    } else {
        // rare fallback (deg>64): lane = channel, serial edges, exact max
        int hd = lane >> 4;
        float bdh = hd == 0 ? bd.x : hd == 1 ? bd.y : hd == 2 ? bd.z : bd.w;
        float mxh = NINF;
        for (int e2 = 0; e2 < deg; ++e2) {
            int s = csr[r0 + e2];
            mxh = fmaxf(mxh, lrelu(asrc[(size_t)s * 4 + hd] + bdh));
        }
        double den = 0.0, aA = 0.0;
        for (int e2 = 0; e2 < deg; ++e2) {
            int s = csr[r0 + e2];
            float ee = expf(lrelu(asrc[(size_t)s * 4 + hd] + bdh) - mxh);
            den += (double)ee;
            aA += (double)ee * (double)h[(size_t)s * 64 + lane];
        }
        am[(size_t)n * 64 + lane] = (float)(aA / (den + 1e-16) / (double)deg);
    }
#undef HLOAD
}

// Streaming GEMM + per-node norm + threshold. Wave = 4 nodes (batched over j).
__global__ __launch_bounds__(256) void k_gemm(
    const float* __restrict__ am, const float* __restrict__ po,
    const float* __restrict__ gamma, const float* __restrict__ beta,
    float* __restrict__ out) {
    __shared__ __align__(16) float w[64][68];
    int tid = threadIdx.x;
    for (int i = tid; i < 4096; i += 256) w[i >> 6][i & 63] = po[i];
    int lane = tid & 63, wv = tid >> 6;
    float gl = gamma[lane], bl = beta[lane];
    __syncthreads();
    const int nb = blockIdx.x * 4 + wv;          // 0..24999, wave-uniform

    double a2[4] = {0.0, 0.0, 0.0, 0.0};
    #pragma unroll
    for (int j = 0; j < 16; ++j) {
        float4 wv4 = *(const float4*)&w[lane][4 * j];        // per-lane b128
        #pragma unroll
        for (int k = 0; k < 4; ++k) {
            float4 amv = *(const float4*)(am + (size_t)(nb + k * 25000) * 64 + 4 * j);
            a2[k] += (double)wv4.x * (double)amv.x;
            a2[k] += (double)wv4.y * (double)amv.y;
            a2[k] += (double)wv4.z * (double)amv.z;
            a2[k] += (double)wv4.w * (double)amv.w;
        }
    }
    #pragma unroll
    for (int k = 0; k < 4; ++k) {
        int n = nb + k * 25000;
        double sum = a2[k];
        #pragma unroll
        for (int off = 32; off; off >>= 1) sum += __shfl_xor(sum, off);
        double mean = sum * (1.0 / 64.0);
        double dv = a2[k] - mean, sq = dv * dv;
        #pragma unroll
        for (int off = 32; off; off >>= 1) sq += __shfl_xor(sq, off);
        double var = sq * (1.0 / 64.0);
        double z = dv / sqrt(var + 1e-5);
        float zf = (float)(z * (double)gl + (double)bl);
        out[(size_t)n * 64 + lane] = (zf >= 2.0f) ? 1.0f : 0.0f;  // LIF fwd == z >= 2
    }
}

extern "C" void kernel_launch(void* const* d_in, const int* in_sizes, int n_in,
                              void* d_out, int out_size, void* d_ws, size_t ws_size,
                              hipStream_t stream) {
    const float* x     = (const float*)d_in[0];
    const int*   ei    = (const int*)d_in[1];   // harness pushes integers as int32
    const float* pw    = (const float*)d_in[2];
    const float* po    = (const float*)d_in[3];
    const float* atts  = (const float*)d_in[4];
    const float* attd  = (const float*)d_in[5];
    const float* gamma = (const float*)d_in[6];
    const float* beta  = (const float*)d_in[7];
    float* out = (float*)d_out;

    char* base = (char*)d_ws;
    size_t off = 0;
    auto alloc = [&](size_t b) { void* p = base + off; off += (b + 255) & ~(size_t)255; return p; };
    float* h      = (float*)alloc((size_t)NN * 64 * 4);
    float* asrc   = (float*)alloc((size_t)NN * 16);
    float* adst   = (float*)alloc((size_t)NN * 16);
    int*   rowptr = (int*)alloc(((size_t)NN + 1) * 4);
    int*   csr    = (int*)alloc((size_t)NE * 4);
    int*   rank   = (int*)alloc((size_t)NE * 4);
    int*   part   = (int*)alloc((size_t)NCH * 4);
    float* amw    = (float*)alloc((size_t)NN * 64 * 4);
    // cnt aliases d_out (only live before k_gemm, which overwrites all of out)
    int* cnt = (int*)out;

    hipMemsetAsync(cnt, 0, (size_t)NN * 4, stream);
    k_count<<<NE / 512, 256, 0, stream>>>(ei, cnt, rank);
    k_scan1<<<NCH, 1024, 0, stream>>>(cnt, part);
    k_scan23<<<NCH, 1024, 0, stream>>>(cnt, part, rowptr);
    k_sp<<<PROJ_BLOCKS + SCAT_BLOCKS, 256, 0, stream>>>(
        ei, rowptr, rank, csr, x, pw, atts, attd, h, asrc, adst);
    k_agg<<<NN / 4, 256, 0, stream>>>(rowptr, csr, asrc, adst, h, amw);
    k_gemm<<<NN / 16, 256, 0, stream>>>(amw, po, gamma, beta, out);
}